// Round 1
// baseline (764.188 us; speedup 1.0000x reference)
//
#include <hip/hip_runtime.h>

#define HH  50    // hidden size
#define RB  16    // batch elements per block (= MFMA N)
#define TT  512   // timesteps
#define FF  4     // input features
#define PA  136   // hA row pitch in u16 (K'=128 + pad)
#define NW  7     // compute waves; each owns 2 row-tiles (wave 6: 1 tile). 7*2 >= 13 tiles
#define NTH ((NW + 1) * 64)   // 512: waves 0..6 compute, wave 7 streams x

typedef __attribute__((ext_vector_type(8))) short bf16x8;   // 8 bf16 = 4 VGPRs
typedef __attribute__((ext_vector_type(4))) float f32x4;    // MFMA accumulator

// fast sigmoid/tanh: v_exp + v_rcp (no fp32 divide expansion)
__device__ __forceinline__ float sigm(float x) {
    return __builtin_amdgcn_rcpf(1.0f + __expf(-x));
}
__device__ __forceinline__ float tanh_f(float x) {
    return fmaf(-2.0f, __builtin_amdgcn_rcpf(1.0f + __expf(2.0f * x)), 1.0f);
}

__device__ __forceinline__ unsigned short f2bf(float f) {   // RNE fp32->bf16 bits
    unsigned u = __float_as_uint(f);
    u += 0x7FFFu + ((u >> 16) & 1u);
    return (unsigned short)(u >> 16);
}
__device__ __forceinline__ float bf2f(unsigned short s) {
    return __uint_as_float(((unsigned)s) << 16);
}
// packed RNE f32->bf16: low16 = bf16(a), high16 = bf16(b). One VALU op replaces
// two 5-instr bit-twiddle converts. (hi/lo split is self-correcting to rounding.)
__device__ __forceinline__ unsigned cvt_pk_bf16(float a, float b) {
    unsigned r;
    asm("v_cvt_pk_bf16_f32 %0, %1, %2" : "=v"(r) : "v"(a), "v"(b));
    return r;
}

// raw barrier: drains LDS ops (producer->consumer ordering) but NOT vmcnt --
// wave 7's in-flight x prefetch stays in flight across the barrier.
__device__ __forceinline__ void block_sync_lds() {
    asm volatile("s_waitcnt lgkmcnt(0)\n\ts_barrier" ::: "memory");
}

// split-bf16 W-frag (A operand) for K' elements kb+0..7. K-layout: k'<4 -> Wx,
// 4<=k'<54 -> Wm, else 0.
__device__ __forceinline__ void buildB(bf16x8& bh, bf16x8& bl,
    const float* Wx, const float* Wm, int row_o, bool rok, int kb) {
    #pragma unroll
    for (int ii = 0; ii < 8; ++ii) {
        const int k = kb + ii;
        float wv = 0.0f;
        if (rok) {
            if (k < FF) { if (Wx) wv = Wx[row_o * FF + k]; }
            else if (k < FF + HH) wv = Wm[row_o * HH + (k - FF)];
        }
        const unsigned short hb = f2bf(wv);
        bh[ii] = (short)hb;
        bl[ii] = (short)f2bf(wv - bf2f(hb));
    }
}

// one LSTM cell elementwise update: s = {i,f,g,o} preactivations, returns h
__device__ __forceinline__ float cell(const f32x4 s, float& c) {
    const float gi = sigm(s[0]);
    const float gf = sigm(s[1]);
    const float gc = tanh_f(s[2]);
    const float go = sigm(s[3]);
    c = fmaf(gf, c, gi * gc);
    return go * tanh_f(c);
}

#define MFMA(a, b, c) __builtin_amdgcn_mfma_f32_16x16x32_bf16(a, b, c, 0, 0, 0)
#define PINB(V) asm volatile("" : "+v"(V));

// 12 register-resident split-bf16 W-frags for one 16-row tile (suffix S)
#define DECL_FRAGS(S, ROWO, ROK) \
    bf16x8 B0h0##S, B0h1##S, B0l0##S, B0l1##S, \
           B1h0##S, B1h1##S, B1l0##S, B1l1##S, \
           B2h0##S, B2h1##S, B2l0##S, B2l1##S; \
    buildB(B0h0##S, B0l0##S, Wih0, Whh0, ROWO, ROK, qk8); \
    buildB(B0h1##S, B0l1##S, Wih0, Whh0, ROWO, ROK, 32 + qk8); \
    buildB(B1h0##S, B1l0##S, nullptr, Wih1, ROWO, ROK, qk8); \
    buildB(B1h1##S, B1l1##S, nullptr, Wih1, ROWO, ROK, 32 + qk8); \
    buildB(B2h0##S, B2l0##S, nullptr, Whh1, ROWO, ROK, qk8); \
    buildB(B2h1##S, B2l1##S, nullptr, Whh1, ROWO, ROK, 32 + qk8); \
    PINB(B0h0##S) PINB(B0h1##S) PINB(B0l0##S) PINB(B0l1##S) \
    PINB(B1h0##S) PINB(B1h1##S) PINB(B1l0##S) PINB(B1l1##S) \
    PINB(B2h0##S) PINB(B2h1##S) PINB(B2l0##S) PINB(B2l1##S)

// layer-0 product: two parallel 3-chains, bias preloaded in ACC
#define L0_MFMA(S, ACC, ACC2) \
    ACC  = MFMA(B0h0##S, A0, ACC);  ACC  = MFMA(B0h1##S, A1, ACC);  ACC  = MFMA(B0h0##S, A2, ACC); \
    ACC2 = MFMA(B0h1##S, A3, ACC2); ACC2 = MFMA(B0l0##S, A0, ACC2); ACC2 = MFMA(B0l1##S, A1, ACC2);

// layer-1 product: ih-chain (P) and hh-chain (Q) in parallel
#define L1_MFMA(S, P, Q) \
    P = MFMA(B1h0##S, A0, P); P = MFMA(B1h1##S, A1, P); P = MFMA(B1h0##S, A2, P); \
    P = MFMA(B1h1##S, A3, P); P = MFMA(B1l0##S, A0, P); P = MFMA(B1l1##S, A1, P); \
    Q = MFMA(B2h0##S, A4, Q); Q = MFMA(B2h1##S, A5, Q); Q = MFMA(B2h0##S, A6, Q); \
    Q = MFMA(B2h1##S, A7, Q); Q = MFMA(B2l0##S, A4, Q); Q = MFMA(B2l1##S, A5, Q);

__attribute__((amdgpu_waves_per_eu(2, 2)))   // 8 waves/block = 2/SIMD -> allow 256 VGPR
__launch_bounds__(NTH)
__global__ void lstm_v11(const float* __restrict__ x,
                         const float* __restrict__ Wih0, const float* __restrict__ Whh0,
                         const float* __restrict__ bih0, const float* __restrict__ bhh0,
                         const float* __restrict__ Wih1, const float* __restrict__ Whh1,
                         const float* __restrict__ bih1, const float* __restrict__ bhh1,
                         const float* __restrict__ fcW,  const float* __restrict__ fcb,
                         float* __restrict__ out)
{
    // ping-pong h buffers (split-bf16 B operands), K-layout [x(4) h_hi(50) .. | x_l(4) h_lo(50) ..]
    __shared__ __align__(16) unsigned short hA0[2][16 * PA];
    __shared__ __align__(16) unsigned short hA1[2][16 * PA];
    __shared__ float h1f[HH * 16];     // final h1 fp32 for FC

    const int tid  = threadIdx.x;
    const int w    = tid >> 6;
    const int lane = tid & 63;
    const int b0   = blockIdx.x * RB;

    const int n15 = lane & 15;
    const int qk  = lane >> 4;
    const int qk8 = qk * 8;
    const int m   = n15;                  // ew batch

    // each compute wave owns tiles t0 = 2w, t1 = 2w+1 (wave 6: only t0=12).
    const int t0 = 2 * w, t1 = 2 * w + 1;
    const bool W2 = (w < NW) && (t1 < 13);

    // ew units for the two tiles: acc regs 0..3 = gates i,f,g,o of unit u for batch m
    const int u0 = t0 * 4 + qk, u1 = t1 * 4 + qk;
    const bool uv0 = (w < NW) && (u0 < HH);
    const bool uv1 = W2 && (u1 < HH);
    const int um0 = uv0 ? u0 : 0, um1 = uv1 ? u1 : 0;

    // W-frag rows (A operand M index) per tile: permuted row' = t*16 + n15
    const int rowp0 = t0 * 16 + n15, rowp1 = t1 * 16 + n15;
    const int runit0 = rowp0 >> 2,  runit1 = rowp1 >> 2;
    const bool rok0 = (w < NW) && (runit0 < HH);
    const bool rok1 = W2 && (runit1 < HH);
    const int row_o0 = rok0 ? (rowp0 & 3) * HH + runit0 : 0;
    const int row_o1 = rok1 ? (rowp1 & 3) * HH + runit1 : 0;

    for (int idx = tid; idx < 16 * PA; idx += NTH) {
        hA0[0][idx] = 0; hA0[1][idx] = 0;
        hA1[0][idx] = 0; hA1[1][idx] = 0;
    }

    // ---- W-frags: 24 register-resident split-bf16 fragments (2 tiles x 12) ----
    DECL_FRAGS(X, row_o0, rok0)
    DECL_FRAGS(Y, row_o1, rok1)

    // bias vectors preloaded into the MFMA C operand (gates of unit u)
    const f32x4 C0a = {bih0[0*HH+um0] + bhh0[0*HH+um0], bih0[1*HH+um0] + bhh0[1*HH+um0],
                       bih0[2*HH+um0] + bhh0[2*HH+um0], bih0[3*HH+um0] + bhh0[3*HH+um0]};
    const f32x4 C0b = {bih0[0*HH+um1] + bhh0[0*HH+um1], bih0[1*HH+um1] + bhh0[1*HH+um1],
                       bih0[2*HH+um1] + bhh0[2*HH+um1], bih0[3*HH+um1] + bhh0[3*HH+um1]};
    const f32x4 C1a = {bih1[0*HH+um0] + bhh1[0*HH+um0], bih1[1*HH+um0] + bhh1[1*HH+um0],
                       bih1[2*HH+um0] + bhh1[2*HH+um0], bih1[3*HH+um0] + bhh1[3*HH+um0]};
    const f32x4 C1b = {bih1[0*HH+um1] + bhh1[0*HH+um1], bih1[1*HH+um1] + bhh1[1*HH+um1],
                       bih1[2*HH+um1] + bhh1[2*HH+um1], bih1[3*HH+um1] + bhh1[3*HH+um1]};

    // wave-7 x prefetch registers (2-iter latency slack; vm never drains at barrier)
    const int xm = lane >> 2, xk = lane & 3;
    float xcur = 0.f, xnxt = 0.f;
    if (w == NW) {
        xcur = x[((size_t)(b0 + xm) * TT + 1) * FF + xk];
        xnxt = x[((size_t)(b0 + xm) * TT + 2) * FF + xk];
    }

    __syncthreads();

    // x(0) into parity-0 buffer
    if (w == 0) {
        const float xv = x[((size_t)(b0 + xm) * TT + 0) * FF + xk];
        const unsigned short hb = f2bf(xv);
        hA0[0][xm * PA + xk]      = hb;
        hA0[0][xm * PA + 64 + xk] = f2bf(xv - bf2f(hb));
    }
    __syncthreads();

    float c0a = 0.f, c0b = 0.f, c1a = 0.f, c1b = 0.f;

    // iter i: gates0(i) from [x(i),h0(i-1)]; gates1(i-1) from h0(i-1),h1(i-2). ONE barrier.
    for (int i = 0; i <= TT; ++i) {
        const int rb = i & 1, wb = (i + 1) & 1;

        if (w < NW) {
            // shared A-frags: read ONCE, used by BOTH tiles (h operand is tile-independent)
            const int ab = n15 * PA + qk8;
            const bf16x8 A0 = *(const bf16x8*)&hA0[rb][ab];
            const bf16x8 A1 = *(const bf16x8*)&hA0[rb][ab + 32];
            const bf16x8 A2 = *(const bf16x8*)&hA0[rb][ab + 64];
            const bf16x8 A3 = *(const bf16x8*)&hA0[rb][ab + 96];
            const bf16x8 A4 = *(const bf16x8*)&hA1[rb][ab];
            const bf16x8 A5 = *(const bf16x8*)&hA1[rb][ab + 32];
            const bf16x8 A6 = *(const bf16x8*)&hA1[rb][ab + 64];
            const bf16x8 A7 = *(const bf16x8*)&hA1[rb][ab + 96];

            f32x4 ga = C0a, gac = {0.f, 0.f, 0.f, 0.f};
            f32x4 gb = C0b, gbc = {0.f, 0.f, 0.f, 0.f};
            f32x4 pa = C1a, qa  = {0.f, 0.f, 0.f, 0.f};
            f32x4 pb = C1b, qb  = {0.f, 0.f, 0.f, 0.f};

            // ---- all MFMAs first (8 independent chains -> deep ILP) ----
            if (i < TT) {
                L0_MFMA(X, ga, gac)
                if (W2) { L0_MFMA(Y, gb, gbc) }
            }
            if (i >= 1) {
                L1_MFMA(X, pa, qa)
                if (W2) { L1_MFMA(Y, pb, qb) }
            }

            // ---- layer-0 elementwise (2 cells, packed bf16 convert) ----
            if (i < TT) {
                const f32x4 s0 = ga + gac;
                const f32x4 s1 = gb + gbc;
                const float hv0 = cell(s0, c0a);
                const float hv1 = cell(s1, c0b);
                const unsigned hp = cvt_pk_bf16(hv0, hv1);
                const unsigned lp = cvt_pk_bf16(hv0 - __uint_as_float(hp << 16),
                                                hv1 - __uint_as_float(hp & 0xFFFF0000u));
                if (uv0) {
                    hA0[wb][m * PA + 4 + u0]  = (unsigned short)hp;
                    hA0[wb][m * PA + 68 + u0] = (unsigned short)lp;
                }
                if (uv1) {
                    hA0[wb][m * PA + 4 + u1]  = (unsigned short)(hp >> 16);
                    hA0[wb][m * PA + 68 + u1] = (unsigned short)(lp >> 16);
                }
            }
            // ---- layer-1 elementwise ----
            if (i >= 1) {
                const f32x4 s0 = pa + qa;
                const f32x4 s1 = pb + qb;
                const float hv0 = cell(s0, c1a);
                const float hv1 = cell(s1, c1b);
                const unsigned hp = cvt_pk_bf16(hv0, hv1);
                const unsigned lp = cvt_pk_bf16(hv0 - __uint_as_float(hp << 16),
                                                hv1 - __uint_as_float(hp & 0xFFFF0000u));
                if (uv0) {
                    hA1[wb][m * PA + 4 + u0]  = (unsigned short)hp;
                    hA1[wb][m * PA + 68 + u0] = (unsigned short)lp;
                    if (i == TT) h1f[u0 * 16 + m] = hv0;
                }
                if (uv1) {
                    hA1[wb][m * PA + 4 + u1]  = (unsigned short)(hp >> 16);
                    hA1[wb][m * PA + 68 + u1] = (unsigned short)(lp >> 16);
                    if (i == TT) h1f[u1 * 16 + m] = hv1;
                }
            }
        } else {
            // wave 7: issue next prefetch FIRST, then publish x(i+1) to write buffer
            float xnew = 0.f;
            if (i + 3 < TT) xnew = x[((size_t)(b0 + xm) * TT + (i + 3)) * FF + xk];
            if (i + 1 < TT) {
                const unsigned short hb = f2bf(xcur);
                hA0[wb][xm * PA + xk]      = hb;
                hA0[wb][xm * PA + 64 + xk] = f2bf(xcur - bf2f(hb));
            }
            xcur = xnxt;
            xnxt = xnew;
        }
        block_sync_lds();
    }

    __syncthreads();

    // ---- final FC: out[b] = fcW @ h1(T-1) + fcb ----
    if (tid < RB * FF) {
        const int r = tid >> 2, ft = tid & 3;
        float s = fcb[ft];
        #pragma unroll
        for (int j = 0; j < HH; j++) s = fmaf(fcW[ft * HH + j], h1f[j * 16 + r], s);
        out[(size_t)(b0 + r) * FF + ft] = s;
    }
}

extern "C" void kernel_launch(void* const* d_in, const int* in_sizes, int n_in,
                              void* d_out, int out_size, void* d_ws, size_t ws_size,
                              hipStream_t stream) {
    const float* x    = (const float*)d_in[0];
    const float* Wih0 = (const float*)d_in[1];
    const float* Whh0 = (const float*)d_in[2];
    const float* bih0 = (const float*)d_in[3];
    const float* bhh0 = (const float*)d_in[4];
    const float* Wih1 = (const float*)d_in[5];
    const float* Whh1 = (const float*)d_in[6];
    const float* bih1 = (const float*)d_in[7];
    const float* bhh1 = (const float*)d_in[8];
    const float* fcW  = (const float*)d_in[9];
    const float* fcb  = (const float*)d_in[10];
    float* out = (float*)d_out;

    const int B = in_sizes[0] / (TT * FF);   // 4096
    lstm_v11<<<B / RB, NTH, 0, stream>>>(x, Wih0, Whh0, bih0, bhh0,
                                         Wih1, Whh1, bih1, bhh1, fcW, fcb, out);
}

// Round 2
// 585.231 us; speedup vs baseline: 1.3058x; 1.3058x over previous
//
#include <hip/hip_runtime.h>

#define HH  50    // hidden size
#define RB  16    // batch elements per block (= MFMA N)
#define TT  512   // timesteps
#define FF  4     // input features
#define PA  72    // hA row pitch in u16 (K'=64 + 8 pad, rows 16B-aligned)
#define NW  13    // compute waves (13 tiles x 16 rows >= 200 permuted gate rows)
#define NTH ((NW + 1) * 64)   // 896: waves 0..12 compute, wave 13 streams x

typedef __attribute__((ext_vector_type(8))) short bf16x8;   // 8 bf16 = 4 VGPRs
typedef __attribute__((ext_vector_type(4))) float f32x4;    // MFMA accumulator

__device__ __forceinline__ unsigned short f2bf(float f) {   // RNE fp32->bf16 bits
    unsigned u = __float_as_uint(f);
    u += 0x7FFFu + ((u >> 16) & 1u);
    return (unsigned short)(u >> 16);
}
__device__ __forceinline__ float bf2f(unsigned short s) {
    return __uint_as_float(((unsigned)s) << 16);
}
// single-instr RNE f32->bf16 (low 16 of result)
__device__ __forceinline__ unsigned cvt_pk_bf16(float a, float b) {
    unsigned r;
    asm("v_cvt_pk_bf16_f32 %0, %1, %2" : "=v"(r) : "v"(a), "v"(b));
    return r;
}

// raw barrier: drains LDS ops (producer->consumer ordering) but NOT vmcnt --
// wave 13's in-flight x prefetch stays in flight across the barrier.
__device__ __forceinline__ void block_sync_lds() {
    asm volatile("s_waitcnt lgkmcnt(0)\n\ts_barrier" ::: "memory");
}

// split-bf16 W-frag (A operand) for K' elements kb+0..7.
// K'-layout: [x_hi(0..3) | h_hi(4..53) | x_lo(54..57) | zero(58..63)]
// hi-frag carries hi(W) at all slots (so hi*x_lo term appears); lo-frag lo(W).
__device__ __forceinline__ void buildB(bf16x8& bh, bf16x8& bl,
    const float* Wx, const float* Wm, int row_o, bool rok, int kb) {
    #pragma unroll
    for (int ii = 0; ii < 8; ++ii) {
        const int k = kb + ii;
        float wv = 0.0f;
        if (rok) {
            if (k < FF) { if (Wx) wv = Wx[row_o * FF + k]; }
            else if (k < FF + HH) wv = Wm[row_o * HH + (k - FF)];
            else if (k < 2 * FF + HH) { if (Wx) wv = Wx[row_o * FF + (k - FF - HH)]; }
        }
        const unsigned short hb = f2bf(wv);
        bh[ii] = (short)hb;
        bl[ii] = (short)f2bf(wv - bf2f(hb));
    }
}

// merged-rcp LSTM cell: sigm(i)*tanh(g) = (1-eg)/((1+ei)(1+eg)) -- one rcp for
// the pair; same for sigm(o)*tanh(c). 8 trans/cell (was 10), algebraically equal.
__device__ __forceinline__ float cell(const f32x4 s, float& c) {
    const float ei = __expf(-s[0]);
    const float ef = __expf(-s[1]);
    const float eg = __expf(-2.0f * s[2]);
    const float eo = __expf(-s[3]);
    const float gf = __builtin_amdgcn_rcpf(1.0f + ef);
    const float t1 = 1.0f + ei;
    const float ig = (1.0f - eg) * __builtin_amdgcn_rcpf(fmaf(eg, t1, t1));
    c = fmaf(gf, c, ig);
    const float ec = __expf(-2.0f * c);
    const float t2 = 1.0f + eo;
    return (1.0f - ec) * __builtin_amdgcn_rcpf(fmaf(ec, t2, t2));
}

#define MFMA(a, b, c) __builtin_amdgcn_mfma_f32_16x16x32_bf16(a, b, c, 0, 0, 0)
#define PINB(V) asm volatile("" : "+v"(V));

__attribute__((amdgpu_waves_per_eu(4, 4)))
__launch_bounds__(NTH)
__global__ void lstm_v12(const float* __restrict__ x,
                         const float* __restrict__ Wih0, const float* __restrict__ Whh0,
                         const float* __restrict__ bih0, const float* __restrict__ bhh0,
                         const float* __restrict__ Wih1, const float* __restrict__ Whh1,
                         const float* __restrict__ bih1, const float* __restrict__ bhh1,
                         const float* __restrict__ fcW,  const float* __restrict__ fcb,
                         float* __restrict__ out)
{
    // ping-pong h buffers; h stored bf16 (single plane), x stored bf16 hi+lo
    __shared__ __align__(16) unsigned short hA0[2][16 * PA];
    __shared__ __align__(16) unsigned short hA1[2][16 * PA];
    __shared__ float h1f[HH * 16];     // final h1 fp32 for FC

    const int tid  = threadIdx.x;
    const int w    = tid >> 6;
    const int lane = tid & 63;
    const int b0   = blockIdx.x * RB;

    const int n15 = lane & 15;
    const int qk  = lane >> 4;
    const int qk8 = qk * 8;

    // D = W . h^T  =>  lane holds D[row'=qk*4+reg][batch=n15]:
    // with row' = 4*unit+gate, acc regs 0..3 = gates i,f,g,o of unit u for batch m.
    const int m = n15;                    // ew batch
    const int u = w * 4 + qk;             // ew unit
    const bool uvalid = (w < NW) && (u < HH);
    const int um = uvalid ? u : 0;

    // W-frag row (A operand M index): permuted row' = w*16 + n15
    const int rowp  = w * 16 + n15;
    const int gidx  = rowp & 3;
    const int runit = rowp >> 2;
    const bool rok  = (w < NW) && (runit < HH);
    const int row_o = rok ? gidx * HH + runit : 0;     // original row g*50+unit

    for (int idx = tid; idx < 16 * PA; idx += NTH) {
        hA0[0][idx] = 0; hA0[1][idx] = 0;
        hA1[0][idx] = 0; hA1[1][idx] = 0;
    }

    // ---- W-frags: 12 register-resident split-bf16 fragments (chunks 0,1 only) ----
    bf16x8 B0h0, B0h1, B0l0, B0l1, B1h0, B1h1, B1l0, B1l1, B2h0, B2h1, B2l0, B2l1;
    buildB(B0h0, B0l0, Wih0, Whh0, row_o, rok, qk8);        // L0: [Wih0 | Whh0]
    buildB(B0h1, B0l1, Wih0, Whh0, row_o, rok, 32 + qk8);
    buildB(B1h0, B1l0, nullptr, Wih1, row_o, rok, qk8);     // L1-ih (vs h0)
    buildB(B1h1, B1l1, nullptr, Wih1, row_o, rok, 32 + qk8);
    buildB(B2h0, B2l0, nullptr, Whh1, row_o, rok, qk8);     // L1-hh (vs h1)
    buildB(B2h1, B2l1, nullptr, Whh1, row_o, rok, 32 + qk8);
    PINB(B0h0) PINB(B0h1) PINB(B0l0) PINB(B0l1)
    PINB(B1h0) PINB(B1h1) PINB(B1l0) PINB(B1l1)
    PINB(B2h0) PINB(B2h1) PINB(B2l0) PINB(B2l1)

    // bias vectors preloaded into the MFMA C operand (gates of unit u)
    const float b0i = bih0[0*HH + um] + bhh0[0*HH + um];
    const float b0f = bih0[1*HH + um] + bhh0[1*HH + um];
    const float b0g = bih0[2*HH + um] + bhh0[2*HH + um];
    const float b0o = bih0[3*HH + um] + bhh0[3*HH + um];
    const float b1i = bih1[0*HH + um] + bhh1[0*HH + um];
    const float b1f = bih1[1*HH + um] + bhh1[1*HH + um];
    const float b1g = bih1[2*HH + um] + bhh1[2*HH + um];
    const float b1o = bih1[3*HH + um] + bhh1[3*HH + um];
    const f32x4 C0 = {b0i, b0f, b0g, b0o};
    const f32x4 C1 = {b1i, b1f, b1g, b1o};

    // wave-13 x prefetch registers (2-iter latency slack; vm never drains at barrier)
    const int xm = lane >> 2, xk = lane & 3;
    float xcur = 0.f, xnxt = 0.f;
    if (w == NW) {
        xcur = x[((size_t)(b0 + xm) * TT + 1) * FF + xk];
        xnxt = x[((size_t)(b0 + xm) * TT + 2) * FF + xk];
    }

    __syncthreads();

    // x(0) into parity-0 buffer (hi + lo planes)
    if (w == 0) {
        const float xv = x[((size_t)(b0 + xm) * TT + 0) * FF + xk];
        const unsigned short hb = f2bf(xv);
        hA0[0][xm * PA + xk]      = hb;
        hA0[0][xm * PA + 54 + xk] = f2bf(xv - bf2f(hb));
    }
    __syncthreads();

    float c0 = 0.f, c1 = 0.f;

    // iter i: gates0(i) from [x(i),h0(i-1)]; gates1(i-1) from h0(i-1),h1(i-2). ONE barrier.
    for (int i = 0; i <= TT; ++i) {
        const int rb = i & 1, wb = (i + 1) & 1;

        if (w < NW) {
            const int ab = n15 * PA + qk8;
            const bf16x8 A0 = *(const bf16x8*)&hA0[rb][ab];
            const bf16x8 A1 = *(const bf16x8*)&hA0[rb][ab + 32];
            const bf16x8 A4 = *(const bf16x8*)&hA1[rb][ab];
            const bf16x8 A5 = *(const bf16x8*)&hA1[rb][ab + 32];

            if (i < TT) {   // ---- layer 0: two parallel 2-chains, bias in C ----
                f32x4 a = C0, a2 = {0.f, 0.f, 0.f, 0.f};
                a  = MFMA(B0h0, A0, a);  a  = MFMA(B0h1, A1, a);
                a2 = MFMA(B0l0, A0, a2); a2 = MFMA(B0l1, A1, a2);
                if (uvalid) {
                    const float h = cell(a + a2, c0);
                    hA0[wb][m * PA + 4 + u] = (unsigned short)cvt_pk_bf16(h, h);
                }
            }
            if (i >= 1) {   // ---- layer 1: four parallel 2-chains ----
                f32x4 p = C1, p2 = {0.f, 0.f, 0.f, 0.f};
                f32x4 q = {0.f, 0.f, 0.f, 0.f}, q2 = {0.f, 0.f, 0.f, 0.f};
                p  = MFMA(B1h0, A0, p);  p  = MFMA(B1h1, A1, p);
                p2 = MFMA(B1l0, A0, p2); p2 = MFMA(B1l1, A1, p2);
                q  = MFMA(B2h0, A4, q);  q  = MFMA(B2h1, A5, q);
                q2 = MFMA(B2l0, A4, q2); q2 = MFMA(B2l1, A5, q2);
                if (uvalid) {
                    const float h = cell((p + p2) + (q + q2), c1);
                    hA1[wb][m * PA + 4 + u] = (unsigned short)cvt_pk_bf16(h, h);
                    if (i == TT) h1f[u * 16 + m] = h;
                }
            }
        } else {
            // wave 13: issue next prefetch FIRST, then publish x(i+1) to write buffer
            float xnew = 0.f;
            if (i + 3 < TT) xnew = x[((size_t)(b0 + xm) * TT + (i + 3)) * FF + xk];
            if (i + 1 < TT) {
                const unsigned short hb = f2bf(xcur);
                hA0[wb][xm * PA + xk]      = hb;
                hA0[wb][xm * PA + 54 + xk] = f2bf(xcur - bf2f(hb));
            }
            xcur = xnxt;
            xnxt = xnew;
        }
        block_sync_lds();
    }

    __syncthreads();

    // ---- final FC: out[b] = fcW @ h1(T-1) + fcb ----
    if (tid < RB * FF) {
        const int r = tid >> 2, ft = tid & 3;
        float s = fcb[ft];
        #pragma unroll
        for (int j = 0; j < HH; j++) s = fmaf(fcW[ft * HH + j], h1f[j * 16 + r], s);
        out[(size_t)(b0 + r) * FF + ft] = s;
    }
}

extern "C" void kernel_launch(void* const* d_in, const int* in_sizes, int n_in,
                              void* d_out, int out_size, void* d_ws, size_t ws_size,
                              hipStream_t stream) {
    const float* x    = (const float*)d_in[0];
    const float* Wih0 = (const float*)d_in[1];
    const float* Whh0 = (const float*)d_in[2];
    const float* bih0 = (const float*)d_in[3];
    const float* bhh0 = (const float*)d_in[4];
    const float* Wih1 = (const float*)d_in[5];
    const float* Whh1 = (const float*)d_in[6];
    const float* bih1 = (const float*)d_in[7];
    const float* bhh1 = (const float*)d_in[8];
    const float* fcW  = (const float*)d_in[9];
    const float* fcb  = (const float*)d_in[10];
    float* out = (float*)d_out;

    const int B = in_sizes[0] / (TT * FF);   // 4096
    lstm_v12<<<B / RB, NTH, 0, stream>>>(x, Wih0, Whh0, bih0, bhh0,
                                         Wih1, Whh1, bih1, bhh1, fcW, fcb, out);
}

// Round 5
// 509.479 us; speedup vs baseline: 1.4999x; 1.1487x over previous
//
#include <hip/hip_runtime.h>

#define HH  50    // hidden size
#define RB  16    // batch elements per block (= MFMA N)
#define TT  512   // timesteps
#define FF  4     // input features
#define PA  72    // hA row pitch in u16 (K'=64 + 8 pad, rows 16B-aligned)
#define NW  13    // compute waves (13 tiles x 16 rows >= 200 permuted gate rows)
#define NTH ((NW + 1) * 64)   // 896: waves 0..12 compute, wave 13 streams x

#define L2E 1.4426950408889634f   // log2(e); gate rows pre-scaled by -L2E / -2*L2E

typedef __attribute__((ext_vector_type(8))) short bf16x8;   // 8 bf16 = 4 VGPRs
typedef __attribute__((ext_vector_type(4))) float f32x4;    // MFMA accumulator

__device__ __forceinline__ unsigned short f2bf(float f) {   // RNE fp32->bf16 bits
    unsigned u = __float_as_uint(f);
    u += 0x7FFFu + ((u >> 16) & 1u);
    return (unsigned short)(u >> 16);
}
__device__ __forceinline__ float bf2f(unsigned short s) {
    return __uint_as_float(((unsigned)s) << 16);
}
// single-instr RNE f32->bf16 (low 16 of result). VOP3, no trans hazard.
__device__ __forceinline__ unsigned cvt_pk_bf16(float a, float b) {
    unsigned r;
    asm("v_cvt_pk_bf16_f32 %0, %1, %2" : "=v"(r) : "v"(a), "v"(b));
    return r;
}
// 2^x via compiler-visible intrinsic ONLY. v_exp_f32 is a TRANS op: a VALU
// consumer needs a hazard wait state, which the compiler inserts for builtins
// but CANNOT insert around opaque inline asm (round-4 NaN lesson).
__device__ __forceinline__ float exp2_fast(float x) {
#if __has_builtin(__builtin_amdgcn_exp2f)
    return __builtin_amdgcn_exp2f(x);
#else
    return __builtin_exp2f(x);   // OCML exp2f: accurate, hazard-safe
#endif
}

// raw barrier: drains LDS ops (producer->consumer ordering) but NOT vmcnt --
// wave 13's in-flight x prefetch stays in flight across the barrier.
__device__ __forceinline__ void block_sync_lds() {
    asm volatile("s_waitcnt lgkmcnt(0)\n\ts_barrier" ::: "memory");
}

// split-bf16 W-frag (A operand) for K' elements kb+0..7, row pre-scaled by `scale`.
// K'-layout: [x_hi(0..3) | h_hi(4..53) | x_lo(54..57) | zero(58..63)]
__device__ __forceinline__ void buildB(bf16x8& bh, bf16x8& bl,
    const float* Wx, const float* Wm, int row_o, bool rok, int kb, float scale) {
    #pragma unroll
    for (int ii = 0; ii < 8; ++ii) {
        const int k = kb + ii;
        float wv = 0.0f;
        if (rok) {
            if (k < FF) { if (Wx) wv = Wx[row_o * FF + k]; }
            else if (k < FF + HH) wv = Wm[row_o * HH + (k - FF)];
            else if (k < 2 * FF + HH) { if (Wx) wv = Wx[row_o * FF + (k - FF - HH)]; }
        }
        wv *= scale;
        const unsigned short hb = f2bf(wv);
        bh[ii] = (short)hb;
        bl[ii] = (short)f2bf(wv - bf2f(hb));
    }
}

// LSTM cell in the log2 domain. s = {i,f,g,o} preacts pre-scaled by -L2E
// (g by -2*L2E); cs carries -2*L2E*c. 5 exp2 + 2 rcp (f-rcp merged into ig-rcp):
//   sig(f) = 1/tf = r*d1 with r = rcp(tf*d1), d1 = (1+ei)(1+eg)
//   sig(i)tanh(g)*(-2L) = (-2L)(1-eg)*r*tf
//   h = sig(o)tanh(c) = (1-ec)/((1+eo)(1+ec)),  ec = 2^cs = e^(-2c)
// cs clamped at 110: keeps ec and to*tc finite; in that regime the merged form
// evaluates to -sigo (the exact limit of sigo*tanh(c) for c -> -inf).
__device__ __forceinline__ float cell(const f32x4 s, float& cs) {
    const float ei = exp2_fast(s[0]);
    const float ef = exp2_fast(s[1]);
    const float eg = exp2_fast(s[2]);
    const float eo = exp2_fast(s[3]);
    const float ti = 1.0f + ei, tf = 1.0f + ef, tg = 1.0f + eg;
    const float d1 = ti * tg;
    const float r  = __builtin_amdgcn_rcpf(d1 * tf);
    const float sigf = r * d1;                             // sigmoid(f)
    const float g1 = fmaf(2.0f * L2E, eg, -2.0f * L2E);    // -2L*(1-eg)
    const float igs = g1 * (r * tf);                       // -2L*sig(i)*tanh(g)
    cs = fminf(fmaf(sigf, cs, igs), 110.0f);               // cs = -2L*c (overflow-guarded)
    const float ec = exp2_fast(cs);
    const float to = 1.0f + eo, tc = 1.0f + ec;
    const float r2 = __builtin_amdgcn_rcpf(to * tc);
    return (1.0f - ec) * r2;                               // h
}

#define MFMA(a, b, c) __builtin_amdgcn_mfma_f32_16x16x32_bf16(a, b, c, 0, 0, 0)
#define PINB(V) asm volatile("" : "+v"(V));

__attribute__((amdgpu_waves_per_eu(4, 4)))
__launch_bounds__(NTH)
__global__ void lstm_v14(const float* __restrict__ x,
                         const float* __restrict__ Wih0, const float* __restrict__ Whh0,
                         const float* __restrict__ bih0, const float* __restrict__ bhh0,
                         const float* __restrict__ Wih1, const float* __restrict__ Whh1,
                         const float* __restrict__ bih1, const float* __restrict__ bhh1,
                         const float* __restrict__ fcW,  const float* __restrict__ fcb,
                         float* __restrict__ out)
{
    // ping-pong h buffers; h stored bf16 (single plane), x stored bf16 hi+lo
    __shared__ __align__(16) unsigned short hA0[2][16 * PA];
    __shared__ __align__(16) unsigned short hA1[2][16 * PA];
    __shared__ float h1f[HH * 16];     // final h1 fp32 for FC

    const int tid  = threadIdx.x;
    const int w    = tid >> 6;
    const int lane = tid & 63;
    const int b0   = blockIdx.x * RB;

    const int n15 = lane & 15;
    const int qk  = lane >> 4;
    const int qk8 = qk * 8;

    // D = W . h^T  =>  lane holds D[row'=qk*4+reg][batch=n15]:
    // with row' = 4*unit+gate, acc regs 0..3 = gates i,f,g,o of unit u for batch m.
    const int m = n15;                    // ew batch
    const int u = w * 4 + qk;             // ew unit
    const bool uvalid = (w < NW) && (u < HH);
    const int um = uvalid ? u : 0;

    // W-frag row (A operand M index): permuted row' = w*16 + n15
    const int rowp  = w * 16 + n15;
    const int gidx  = rowp & 3;
    const int runit = rowp >> 2;
    const bool rok  = (w < NW) && (runit < HH);
    const int row_o = rok ? gidx * HH + runit : 0;     // original row g*50+unit
    const float wscale = (gidx == 2) ? (-2.0f * L2E) : (-L2E);   // g-gate rows x2

    for (int idx = tid; idx < 16 * PA; idx += NTH) {
        hA0[0][idx] = 0; hA0[1][idx] = 0;
        hA1[0][idx] = 0; hA1[1][idx] = 0;
    }

    // ---- W-frags: 12 register-resident split-bf16 fragments (pre-scaled) ----
    bf16x8 B0h0, B0h1, B0l0, B0l1, B1h0, B1h1, B1l0, B1l1, B2h0, B2h1, B2l0, B2l1;
    buildB(B0h0, B0l0, Wih0, Whh0, row_o, rok, qk8, wscale);        // L0: [Wih0 | Whh0]
    buildB(B0h1, B0l1, Wih0, Whh0, row_o, rok, 32 + qk8, wscale);
    buildB(B1h0, B1l0, nullptr, Wih1, row_o, rok, qk8, wscale);     // L1-ih (vs h0)
    buildB(B1h1, B1l1, nullptr, Wih1, row_o, rok, 32 + qk8, wscale);
    buildB(B2h0, B2l0, nullptr, Whh1, row_o, rok, qk8, wscale);     // L1-hh (vs h1)
    buildB(B2h1, B2l1, nullptr, Whh1, row_o, rok, 32 + qk8, wscale);
    PINB(B0h0) PINB(B0h1) PINB(B0l0) PINB(B0l1)
    PINB(B1h0) PINB(B1h1) PINB(B1l0) PINB(B1l1)
    PINB(B2h0) PINB(B2h1) PINB(B2l0) PINB(B2l1)

    // bias vectors preloaded into the MFMA C operand (gates i,f,g,o of unit u),
    // scaled into the log2 domain (i,f,o: -L2E; g: -2*L2E)
    const f32x4 C0 = {-L2E        * (bih0[0*HH + um] + bhh0[0*HH + um]),
                      -L2E        * (bih0[1*HH + um] + bhh0[1*HH + um]),
                      -2.0f * L2E * (bih0[2*HH + um] + bhh0[2*HH + um]),
                      -L2E        * (bih0[3*HH + um] + bhh0[3*HH + um])};
    const f32x4 C1 = {-L2E        * (bih1[0*HH + um] + bhh1[0*HH + um]),
                      -L2E        * (bih1[1*HH + um] + bhh1[1*HH + um]),
                      -2.0f * L2E * (bih1[2*HH + um] + bhh1[2*HH + um]),
                      -L2E        * (bih1[3*HH + um] + bhh1[3*HH + um])};
    const f32x4 Z0 = {0.f, 0.f, 0.f, 0.f};   // loop-invariant zero seed

    // wave-13 x prefetch registers (2-iter latency slack; vm never drains at barrier)
    const int xm = lane >> 2, xk = lane & 3;
    float xcur = 0.f, xnxt = 0.f;
    if (w == NW) {
        xcur = x[((size_t)(b0 + xm) * TT + 1) * FF + xk];
        xnxt = x[((size_t)(b0 + xm) * TT + 2) * FF + xk];
    }

    __syncthreads();

    // x(0) into parity-0 buffer (hi + lo planes)
    if (w == 0) {
        const float xv = x[((size_t)(b0 + xm) * TT + 0) * FF + xk];
        const unsigned short hb = f2bf(xv);
        hA0[0][xm * PA + xk]      = hb;
        hA0[0][xm * PA + 54 + xk] = f2bf(xv - bf2f(hb));
    }
    __syncthreads();

    float c0 = 0.f, c1 = 0.f;   // carried as cs = -2*L2E*c

    // iter i: gates0(i) from [x(i),h0(i-1)]; gates1(i-1) from h0(i-1),h1(i-2). ONE barrier.
    for (int i = 0; i <= TT; ++i) {
        const int rb = i & 1, wb = (i + 1) & 1;

        if (w < NW) {
            const int ab = n15 * PA + qk8;
            const bf16x8 A0 = *(const bf16x8*)&hA0[rb][ab];
            const bf16x8 A1 = *(const bf16x8*)&hA0[rb][ab + 32];
            const bf16x8 A4 = *(const bf16x8*)&hA1[rb][ab];
            const bf16x8 A5 = *(const bf16x8*)&hA1[rb][ab + 32];

            if (i < TT) {   // ---- layer 0: single 4-chain seeded from C0 ----
                f32x4 a = C0;
                a = MFMA(B0h0, A0, a); a = MFMA(B0h1, A1, a);
                a = MFMA(B0l0, A0, a); a = MFMA(B0l1, A1, a);
                if (uvalid) {
                    const float h = cell(a, c0);
                    hA0[wb][m * PA + 4 + u] = (unsigned short)cvt_pk_bf16(h, h);
                }
            }
            if (i >= 1) {   // ---- layer 1: two 4-chains (C1 seed + zero seed) ----
                f32x4 p = C1, q = Z0;
                p = MFMA(B1h0, A0, p); p = MFMA(B1h1, A1, p);
                p = MFMA(B1l0, A0, p); p = MFMA(B1l1, A1, p);
                q = MFMA(B2h0, A4, q); q = MFMA(B2h1, A5, q);
                q = MFMA(B2l0, A4, q); q = MFMA(B2l1, A5, q);
                if (uvalid) {
                    const float h = cell(p + q, c1);
                    hA1[wb][m * PA + 4 + u] = (unsigned short)cvt_pk_bf16(h, h);
                    if (i == TT) h1f[u * 16 + m] = h;
                }
            }
        } else {
            // wave 13: issue next prefetch FIRST, then publish x(i+1) to write buffer
            float xnew = 0.f;
            if (i + 3 < TT) xnew = x[((size_t)(b0 + xm) * TT + (i + 3)) * FF + xk];
            if (i + 1 < TT) {
                const unsigned short hb = f2bf(xcur);
                hA0[wb][xm * PA + xk]      = hb;
                hA0[wb][xm * PA + 54 + xk] = f2bf(xcur - bf2f(hb));
            }
            xcur = xnxt;
            xnxt = xnew;
        }
        block_sync_lds();
    }

    __syncthreads();

    // ---- final FC: out[b] = fcW @ h1(T-1) + fcb ----
    if (tid < RB * FF) {
        const int r = tid >> 2, ft = tid & 3;
        float s = fcb[ft];
        #pragma unroll
        for (int j = 0; j < HH; j++) s = fmaf(fcW[ft * HH + j], h1f[j * 16 + r], s);
        out[(size_t)(b0 + r) * FF + ft] = s;
    }
}

extern "C" void kernel_launch(void* const* d_in, const int* in_sizes, int n_in,
                              void* d_out, int out_size, void* d_ws, size_t ws_size,
                              hipStream_t stream) {
    const float* x    = (const float*)d_in[0];
    const float* Wih0 = (const float*)d_in[1];
    const float* Whh0 = (const float*)d_in[2];
    const float* bih0 = (const float*)d_in[3];
    const float* bhh0 = (const float*)d_in[4];
    const float* Wih1 = (const float*)d_in[5];
    const float* Whh1 = (const float*)d_in[6];
    const float* bih1 = (const float*)d_in[7];
    const float* bhh1 = (const float*)d_in[8];
    const float* fcW  = (const float*)d_in[9];
    const float* fcb  = (const float*)d_in[10];
    float* out = (float*)d_out;

    const int B = in_sizes[0] / (TT * FF);   // 4096
    lstm_v14<<<B / RB, NTH, 0, stream>>>(x, Wih0, Whh0, bih0, bhh0,
                                         Wih1, Whh1, bih1, bhh1, fcW, fcb, out);
}